// Round 1
// baseline (648.529 us; speedup 1.0000x reference)
//
#include <hip/hip_runtime.h>
#include <math.h>

// Problem constants (reference: embeddings [16,512,256] fp32, labels [16,512] int)
#define H       256      // embedding dim
#define BI      64       // anchors per block tile
#define BJ      64       // j's per tile
#define KC      32       // K chunk staged in LDS
#define NSPLIT  4        // j-range splits (grid.y) for parallelism
#define BIGV    1e9f
#define IGNORE_IDX (-100)

// ---------------- Kernel 1: L2-normalize rows (one wave per row) ----------------
__global__ __launch_bounds__(256) void norm_kernel(const float* __restrict__ in,
                                                   float* __restrict__ out) {
    int row  = blockIdx.x * 4 + (threadIdx.x >> 6);
    int lane = threadIdx.x & 63;
    const float4* ip = (const float4*)(in + (size_t)row * H);
    float4 v = ip[lane];                       // 64 lanes x 4 floats = 256
    float ss = v.x*v.x + v.y*v.y + v.z*v.z + v.w*v.w;
    #pragma unroll
    for (int off = 32; off >= 1; off >>= 1) ss += __shfl_xor(ss, off);
    float scale = 1.0f / fmaxf(sqrtf(ss), 1e-12f);
    float4 o = make_float4(v.x*scale, v.y*scale, v.z*scale, v.w*scale);
    ((float4*)(out + (size_t)row * H))[lane] = o;
}

// ---------------- Kernel 2: tiled sim + masked min/max reduction ----------------
// grid = (N/BI, NSPLIT), block = 256 (16x16 threads, each owns a 4x4 sim tile).
// Writes per-(anchor, split) partial hardest-pos (min) and hardest-neg (max).
__global__ __launch_bounds__(256) void sim_kernel(const float* __restrict__ e,
                                                  const int* __restrict__ lab,
                                                  float* __restrict__ pmin,
                                                  float* __restrict__ pmax, int N) {
    __shared__ float As[KC][BI + 4];   // [k][i], +4 pad: 16B-aligned rows, 2-way bank max
    __shared__ float Bs[KC][BJ + 4];
    __shared__ int labJ[BJ];

    const int tid = threadIdx.x;
    const int tx = tid & 15;           // j group (4 cols each)
    const int ty = tid >> 4;           // i group (4 rows each)
    const int aBase  = blockIdx.x * BI;
    const int jChunk = N / NSPLIT;
    const int jStart = blockIdx.y * jChunk;

    int myA[4]; int myLab[4];
    #pragma unroll
    for (int r = 0; r < 4; ++r) { myA[r] = aBase + ty * 4 + r; myLab[r] = lab[myA[r]]; }

    float runMin[4] = {BIGV, BIGV, BIGV, BIGV};
    float runMax[4] = {-BIGV, -BIGV, -BIGV, -BIGV};

    for (int j0 = jStart; j0 < jStart + jChunk; j0 += BJ) {
        if (tid < BJ) labJ[tid] = lab[j0 + tid];
        float c[4][4] = {};
        for (int kc = 0; kc < H; kc += KC) {
            __syncthreads();
            // stage A and B chunks (transposed to k-major), 8 floats each per thread
            #pragma unroll
            for (int it = 0; it < (BI * KC) / 256; ++it) {
                int idx = it * 256 + tid;
                int k = idx & (KC - 1);
                int i = idx >> 5;
                As[k][i] = e[(size_t)(aBase + i) * H + kc + k];
                Bs[k][i] = e[(size_t)(j0    + i) * H + kc + k];
            }
            __syncthreads();
            #pragma unroll
            for (int k = 0; k < KC; ++k) {
                float4 a4 = *(const float4*)&As[k][ty * 4];
                float4 b4 = *(const float4*)&Bs[k][tx * 4];
                float av[4] = {a4.x, a4.y, a4.z, a4.w};
                float bv[4] = {b4.x, b4.y, b4.z, b4.w};
                #pragma unroll
                for (int r = 0; r < 4; ++r)
                    #pragma unroll
                    for (int q = 0; q < 4; ++q)
                        c[r][q] = fmaf(av[r], bv[q], c[r][q]);
            }
        }
        // fold sim tile into running masked min/max
        #pragma unroll
        for (int r = 0; r < 4; ++r) {
            int la = myLab[r];
            bool anchorConf = (la >= 1 && la <= 6);
            int partner = ((la - 1) ^ 1) + 1;       // only meaningful when anchorConf
            #pragma unroll
            for (int q = 0; q < 4; ++q) {
                int lj = labJ[tx * 4 + q];
                bool validJ = (lj != IGNORE_IDX);
                int gj = j0 + tx * 4 + q;
                float s = c[r][q];
                if (validJ && lj == la && gj != myA[r]) runMin[r] = fminf(runMin[r], s);
                if (validJ && anchorConf && lj == partner) runMax[r] = fmaxf(runMax[r], s);
            }
        }
        __syncthreads();   // protect labJ/LDS before next tile's writes
    }

    // reduce across the 16 tx threads (same wave 16-lane subgroup)
    #pragma unroll
    for (int r = 0; r < 4; ++r) {
        #pragma unroll
        for (int off = 1; off < 16; off <<= 1) {
            runMin[r] = fminf(runMin[r], __shfl_xor(runMin[r], off));
            runMax[r] = fmaxf(runMax[r], __shfl_xor(runMax[r], off));
        }
        if (tx == 0) {
            pmin[(size_t)myA[r] * NSPLIT + blockIdx.y] = runMin[r];
            pmax[(size_t)myA[r] * NSPLIT + blockIdx.y] = runMax[r];
        }
    }
}

// ---------------- Kernel 3: per-anchor triplet + loss reduction ----------------
__global__ __launch_bounds__(1024) void finalize_kernel(const int* __restrict__ lab,
                                                        const float* __restrict__ pmin,
                                                        const float* __restrict__ pmax,
                                                        float* __restrict__ out, int N) {
    float sum = 0.f; int cnt = 0;
    for (int a = threadIdx.x; a < N; a += 1024) {
        int la = lab[a];
        bool ok = (la >= 1 && la <= 6);           // valid && in a confused pair
        float hp = BIGV, hn = -BIGV;
        #pragma unroll
        for (int s = 0; s < NSPLIT; ++s) {
            hp = fminf(hp, pmin[(size_t)a * NSPLIT + s]);
            hn = fmaxf(hn, pmax[(size_t)a * NSPLIT + s]);
        }
        bool hasP = hp < 0.5f * BIGV;
        bool hasN = hn > -0.5f * BIGV;
        if (ok && hasP && hasN) {
            cnt += 1;
            float t = 0.5f + hn - hp;             // MARGIN = 0.5
            if (t > 0.f) sum += t;
        }
    }
    #pragma unroll
    for (int off = 32; off >= 1; off >>= 1) {
        sum += __shfl_xor(sum, off);
        cnt += __shfl_xor(cnt, off);
    }
    __shared__ float ssum[16]; __shared__ int scnt[16];
    int wave = threadIdx.x >> 6, lane = threadIdx.x & 63;
    if (lane == 0) { ssum[wave] = sum; scnt[wave] = cnt; }
    __syncthreads();
    if (threadIdx.x == 0) {
        float ts = 0.f; int tc = 0;
        #pragma unroll
        for (int w = 0; w < 16; ++w) { ts += ssum[w]; tc += scnt[w]; }
        out[0] = (tc > 0) ? ts / (float)tc : 0.f;
    }
}

extern "C" void kernel_launch(void* const* d_in, const int* in_sizes, int n_in,
                              void* d_out, int out_size, void* d_ws, size_t ws_size,
                              hipStream_t stream) {
    const float* emb = (const float*)d_in[0];
    const int*   lab = (const int*)d_in[1];
    int N = in_sizes[1];                 // 8192

    float* eN   = (float*)d_ws;          // N*H normalized embeddings (8 MB)
    float* pmin = eN + (size_t)N * H;    // N*NSPLIT partial hardest-pos
    float* pmax = pmin + (size_t)N * NSPLIT;

    norm_kernel<<<N / 4, 256, 0, stream>>>(emb, eN);
    sim_kernel<<<dim3(N / BI, NSPLIT), 256, 0, stream>>>(eN, lab, pmin, pmax, N);
    finalize_kernel<<<1, 1024, 0, stream>>>(lab, pmin, pmax, (float*)d_out, N);
}

// Round 2
// 196.410 us; speedup vs baseline: 3.3019x; 3.3019x over previous
//
#include <hip/hip_runtime.h>
#include <math.h>

#define Hdim   256       // embedding dim
#define NS     16        // j-range splits (grid.y)
#define MT     32        // anchors per wave (2 x 16-row MFMA tiles)
#define WPB    4         // waves per block
#define BIGV   1e9f
#define MARGIN 0.5f

typedef __attribute__((ext_vector_type(8))) short bf16x8;   // MFMA A/B frag (4 VGPRs)
typedef __attribute__((ext_vector_type(4))) float f32x4;    // MFMA C/D frag

// fp32 -> bf16 round-to-nearest-even
__device__ inline unsigned short f2bf(float f) {
    unsigned u = __float_as_uint(f);
    unsigned r = (u + 0x7fffu + ((u >> 16) & 1u)) >> 16;
    return (unsigned short)r;
}
// order-preserving float -> uint key (monotone increasing)
__device__ inline unsigned fkey(float f) {
    unsigned u = __float_as_uint(f);
    return (u & 0x80000000u) ? ~u : (u | 0x80000000u);
}
__device__ inline float funkey(unsigned k) {
    unsigned u = (k & 0x80000000u) ? (k & 0x7fffffffu) : ~k;
    return __uint_as_float(u);
}

// ------------- Kernel 1: L2-normalize rows -> bf16, and init key arrays -------------
__global__ __launch_bounds__(256) void norm_kernel(const float* __restrict__ in,
                                                   unsigned short* __restrict__ out,
                                                   unsigned* __restrict__ pminK,
                                                   unsigned* __restrict__ pmaxK, int N) {
    int row  = blockIdx.x * 4 + (threadIdx.x >> 6);
    int lane = threadIdx.x & 63;
    float4 v = ((const float4*)(in + (size_t)row * Hdim))[lane];
    float ss = v.x*v.x + v.y*v.y + v.z*v.z + v.w*v.w;
    #pragma unroll
    for (int off = 32; off >= 1; off >>= 1) ss += __shfl_xor(ss, off);
    float sc = 1.0f / fmaxf(sqrtf(ss), 1e-12f);
    ushort4 o;
    o.x = f2bf(v.x * sc); o.y = f2bf(v.y * sc);
    o.z = f2bf(v.z * sc); o.w = f2bf(v.w * sc);
    ((ushort4*)(out + (size_t)row * Hdim))[lane] = o;
    // init sentinel keys (ws is re-poisoned before every launch)
    int g = blockIdx.x * 256 + threadIdx.x;
    if (g < N) { pminK[g] = 0xFFFFFFFFu; pmaxK[g] = 0u; }
}

// ------------- Kernel 2: MFMA sim tiles + masked min/max, atomic-key combine -------------
// grid = (N/(WPB*MT), NS), block = 256 (4 independent waves; no LDS, no barriers).
// Wave w: anchors [aBase, aBase+32) vs j-chunk [jStart, jStart+N/NS).
__global__ __launch_bounds__(256) void sim_kernel(const unsigned short* __restrict__ ebf,
                                                  const int* __restrict__ lab,
                                                  unsigned* __restrict__ pminK,
                                                  unsigned* __restrict__ pmaxK, int N) {
    const int wave = threadIdx.x >> 6;
    const int lane = threadIdx.x & 63;
    const int col  = lane & 15;     // MFMA n / C col
    const int quad = lane >> 4;     // MFMA k-group / C row-group
    const int aBase  = (blockIdx.x * WPB + wave) * MT;
    const int jChunk = N / NS;
    const int jStart = blockIdx.y * jChunk;

    // A fragments resident: frag[m=lane&15][k=quad*8+j] = 16B contiguous global load
    bf16x8 afrag[2][8];
    #pragma unroll
    for (int t = 0; t < 2; ++t) {
        const unsigned short* rp = ebf + (size_t)(aBase + t * 16 + col) * Hdim + quad * 8;
        #pragma unroll
        for (int ks = 0; ks < 8; ++ks)
            afrag[t][ks] = *(const bf16x8*)(rp + ks * 32);
    }

    // per-(tile, reg) anchor label / confused partner / global index (C row = quad*4+r)
    int la[2][4], pn[2][4], ga[2][4];
    #pragma unroll
    for (int t = 0; t < 2; ++t)
        #pragma unroll
        for (int r = 0; r < 4; ++r) {
            int a = aBase + t * 16 + quad * 4 + r;
            ga[t][r] = a;
            int l = lab[a];
            la[t][r] = l;
            pn[t][r] = (l >= 1 && l <= 6) ? (((l - 1) ^ 1) + 1) : -1;  // pairs (1,2)(3,4)(5,6)
        }

    float runMin[2][4], runMax[2][4];
    #pragma unroll
    for (int t = 0; t < 2; ++t)
        #pragma unroll
        for (int r = 0; r < 4; ++r) { runMin[t][r] = BIGV; runMax[t][r] = -BIGV; }

    for (int j0 = jStart; j0 < jStart + jChunk; j0 += 16) {
        bf16x8 bfrag[8];   // B frag: same addressing as A (sim = E * E^T)
        const unsigned short* rp = ebf + (size_t)(j0 + col) * Hdim + quad * 8;
        #pragma unroll
        for (int ks = 0; ks < 8; ++ks)
            bfrag[ks] = *(const bf16x8*)(rp + ks * 32);
        int lj = lab[j0 + col];
        int gj = j0 + col;

        #pragma unroll
        for (int t = 0; t < 2; ++t) {
            f32x4 acc = {0.f, 0.f, 0.f, 0.f};
            #pragma unroll
            for (int ks = 0; ks < 8; ++ks)
                acc = __builtin_amdgcn_mfma_f32_16x16x32_bf16(afrag[t][ks], bfrag[ks], acc, 0, 0, 0);
            #pragma unroll
            for (int r = 0; r < 4; ++r) {
                float s = acc[r];
                bool pos = (lj == la[t][r]) & (gj != ga[t][r]);   // same class, not self
                bool neg = (lj == pn[t][r]);                      // confused-pair class
                runMin[t][r] = fminf(runMin[t][r], pos ? s : BIGV);
                runMax[t][r] = fmaxf(runMax[t][r], neg ? s : -BIGV);
            }
        }
    }

    // reduce across the 16 cols (xor shuffles stay inside the 16-lane group)
    #pragma unroll
    for (int t = 0; t < 2; ++t)
        #pragma unroll
        for (int r = 0; r < 4; ++r) {
            float mn = runMin[t][r], mx = runMax[t][r];
            #pragma unroll
            for (int off = 1; off < 16; off <<= 1) {
                mn = fminf(mn, __shfl_xor(mn, off));
                mx = fmaxf(mx, __shfl_xor(mx, off));
            }
            if (col == 0) {
                int a = ga[t][r];
                if (mn < 1e8f)  atomicMin(&pminK[a], fkey(mn));   // commutative -> deterministic
                if (mx > -1e8f) atomicMax(&pmaxK[a], fkey(mx));
            }
        }
}

// ------------- Kernel 3: per-anchor triplet + loss -------------
__global__ __launch_bounds__(1024) void finalize_kernel(const int* __restrict__ lab,
                                                        const unsigned* __restrict__ pminK,
                                                        const unsigned* __restrict__ pmaxK,
                                                        float* __restrict__ out, int N) {
    float sum = 0.f; int cnt = 0;
    for (int a = threadIdx.x; a < N; a += 1024) {
        int l = lab[a];
        bool ok = (l >= 1 && l <= 6);
        unsigned kp = pminK[a], kn = pmaxK[a];
        if (ok && kp != 0xFFFFFFFFu && kn != 0u) {
            float hp = funkey(kp), hn = funkey(kn);
            float t = MARGIN + hn - hp;
            if (t > 0.f) sum += t;
            cnt += 1;
        }
    }
    #pragma unroll
    for (int off = 32; off >= 1; off >>= 1) {
        sum += __shfl_xor(sum, off);
        cnt += __shfl_xor(cnt, off);
    }
    __shared__ float ssum[16]; __shared__ int scnt[16];
    int w = threadIdx.x >> 6, lane = threadIdx.x & 63;
    if (lane == 0) { ssum[w] = sum; scnt[w] = cnt; }
    __syncthreads();
    if (threadIdx.x == 0) {
        float ts = 0.f; int tc = 0;
        #pragma unroll
        for (int i = 0; i < 16; ++i) { ts += ssum[i]; tc += scnt[i]; }
        out[0] = (tc > 0) ? ts / (float)tc : 0.f;
    }
}

extern "C" void kernel_launch(void* const* d_in, const int* in_sizes, int n_in,
                              void* d_out, int out_size, void* d_ws, size_t ws_size,
                              hipStream_t stream) {
    const float* emb = (const float*)d_in[0];
    const int*   lab = (const int*)d_in[1];
    int N = in_sizes[1];                               // 8192

    unsigned short* ebf  = (unsigned short*)d_ws;      // N*256 bf16 (4 MB)
    unsigned*       pminK = (unsigned*)(ebf + (size_t)N * Hdim);
    unsigned*       pmaxK = pminK + N;

    norm_kernel<<<N / 4, 256, 0, stream>>>(emb, ebf, pminK, pmaxK, N);
    sim_kernel<<<dim3(N / (WPB * MT), NS), 256, 0, stream>>>(ebf, lab, pminK, pmaxK, N);
    finalize_kernel<<<1, 1024, 0, stream>>>(lab, pminK, pmaxK, (float*)d_out, N);
}

// Round 3
// 192.251 us; speedup vs baseline: 3.3733x; 1.0216x over previous
//
#include <hip/hip_runtime.h>
#include <math.h>

#define Hdim   256       // embedding dim
#define NS     16        // j-range splits (grid.y)
#define MT     32        // anchors per wave (2 x 16-row MFMA tiles)
#define WPB    4         // waves per block
#define BIGV   1e9f
#define MARGIN 0.5f

typedef __attribute__((ext_vector_type(8))) short bf16x8;   // MFMA A/B frag (4 VGPRs)
typedef __attribute__((ext_vector_type(4))) float f32x4;    // MFMA C/D frag

// fp32 -> bf16 round-to-nearest-even
__device__ inline unsigned short f2bf(float f) {
    unsigned u = __float_as_uint(f);
    unsigned r = (u + 0x7fffu + ((u >> 16) & 1u)) >> 16;
    return (unsigned short)r;
}
// order-preserving float -> uint key (monotone increasing)
__device__ inline unsigned fkey(float f) {
    unsigned u = __float_as_uint(f);
    return (u & 0x80000000u) ? ~u : (u | 0x80000000u);
}
__device__ inline float funkey(unsigned k) {
    unsigned u = (k & 0x80000000u) ? (k & 0x7fffffffu) : ~k;
    return __uint_as_float(u);
}

// ------------- Kernel 1: L2-normalize rows -> bf16, and init key arrays -------------
__global__ __launch_bounds__(256) void norm_kernel(const float* __restrict__ in,
                                                   unsigned short* __restrict__ out,
                                                   unsigned* __restrict__ pminK,
                                                   unsigned* __restrict__ pmaxK, int N) {
    int row  = blockIdx.x * 4 + (threadIdx.x >> 6);
    int lane = threadIdx.x & 63;
    float4 v = ((const float4*)(in + (size_t)row * Hdim))[lane];
    float ss = v.x*v.x + v.y*v.y + v.z*v.z + v.w*v.w;
    #pragma unroll
    for (int off = 32; off >= 1; off >>= 1) ss += __shfl_xor(ss, off);
    float sc = 1.0f / fmaxf(sqrtf(ss), 1e-12f);
    ushort4 o;
    o.x = f2bf(v.x * sc); o.y = f2bf(v.y * sc);
    o.z = f2bf(v.z * sc); o.w = f2bf(v.w * sc);
    ((ushort4*)(out + (size_t)row * Hdim))[lane] = o;
    int g = blockIdx.x * 256 + threadIdx.x;
    if (g < N) { pminK[g] = 0xFFFFFFFFu; pmaxK[g] = 0u; }
}

// ------------- Kernel 2: MFMA sim + masked min/max, register-double-buffered j-loop -------------
// grid = (N/(WPB*MT), NS), block = 256 (4 independent waves; no LDS, no barriers).
__global__ __launch_bounds__(256) void sim_kernel(const unsigned short* __restrict__ ebf,
                                                  const int* __restrict__ lab,
                                                  unsigned* __restrict__ pminK,
                                                  unsigned* __restrict__ pmaxK, int N) {
    const int wave = threadIdx.x >> 6;
    const int lane = threadIdx.x & 63;
    const int col  = lane & 15;     // MFMA n / C col
    const int quad = lane >> 4;     // MFMA k-group / C row-group
    const int aBase  = (blockIdx.x * WPB + wave) * MT;
    const int jChunk = N / NS;
    const int jStart = blockIdx.y * jChunk;

    // A fragments resident: frag[m=lane&15][k=quad*8+j]
    bf16x8 afrag[2][8];
    #pragma unroll
    for (int t = 0; t < 2; ++t) {
        const unsigned short* rp = ebf + (size_t)(aBase + t * 16 + col) * Hdim + quad * 8;
        #pragma unroll
        for (int ks = 0; ks < 8; ++ks)
            afrag[t][ks] = *(const bf16x8*)(rp + ks * 32);
    }

    // per-(tile, reg) anchor label / confused partner (C row = quad*4+r)
    int la[2][4], pn[2][4];
    #pragma unroll
    for (int t = 0; t < 2; ++t)
        #pragma unroll
        for (int r = 0; r < 4; ++r) {
            int l = lab[aBase + t * 16 + quad * 4 + r];
            la[t][r] = l;
            pn[t][r] = (l >= 1 && l <= 6) ? (((l - 1) ^ 1) + 1) : -1;  // pairs (1,2)(3,4)(5,6)
        }

    float runMin[2][4], runMax[2][4];
    #pragma unroll
    for (int t = 0; t < 2; ++t)
        #pragma unroll
        for (int r = 0; r < 4; ++r) { runMin[t][r] = BIGV; runMax[t][r] = -BIGV; }

    bf16x8 b0[8], b1[8];
    int lj0, lj1;

    auto loadB = [&](bf16x8 (&bf)[8], int& lj, int j0) {
        lj = lab[j0 + col];
        const unsigned short* rp = ebf + (size_t)(j0 + col) * Hdim + quad * 8;
        #pragma unroll
        for (int ks = 0; ks < 8; ++ks)
            bf[ks] = *(const bf16x8*)(rp + ks * 32);
    };

    auto computeTile = [&](bf16x8 (&bf)[8], int lj, int j0) {
        #pragma unroll
        for (int t = 0; t < 2; ++t) {
            f32x4 acc = {0.f, 0.f, 0.f, 0.f};
            #pragma unroll
            for (int ks = 0; ks < 8; ++ks)
                acc = __builtin_amdgcn_mfma_f32_16x16x32_bf16(afrag[t][ks], bf[ks], acc, 0, 0, 0);
            if (j0 == aBase + t * 16) {          // wave-uniform: diagonal tile
                #pragma unroll
                for (int r = 0; r < 4; ++r) {
                    float s = acc[r];
                    bool pos = (lj == la[t][r]) & (col != quad * 4 + r);
                    bool neg = (lj == pn[t][r]);
                    runMin[t][r] = fminf(runMin[t][r], pos ? s : BIGV);
                    runMax[t][r] = fmaxf(runMax[t][r], neg ? s : -BIGV);
                }
            } else {
                #pragma unroll
                for (int r = 0; r < 4; ++r) {
                    float s = acc[r];
                    bool pos = (lj == la[t][r]);
                    bool neg = (lj == pn[t][r]);
                    runMin[t][r] = fminf(runMin[t][r], pos ? s : BIGV);
                    runMax[t][r] = fmaxf(runMax[t][r], neg ? s : -BIGV);
                }
            }
        }
    };

    // software pipeline: ping-pong b0/b1, next tile's loads in flight across compute
    loadB(b0, lj0, jStart);
    const int nPair = jChunk / 32;
    for (int i = 0; i < nPair; ++i) {
        int jA = jStart + i * 32;
        int jB = jA + 16;
        int jC = jA + 32;
        if (jC >= jStart + jChunk) jC = jStart;   // harmless dummy reload on last iter
        loadB(b1, lj1, jB);
        computeTile(b0, lj0, jA);
        loadB(b0, lj0, jC);
        computeTile(b1, lj1, jB);
    }

    // reduce across the 16 cols (xor shuffles stay inside the 16-lane group)
    #pragma unroll
    for (int t = 0; t < 2; ++t)
        #pragma unroll
        for (int r = 0; r < 4; ++r) {
            float mn = runMin[t][r], mx = runMax[t][r];
            #pragma unroll
            for (int off = 1; off < 16; off <<= 1) {
                mn = fminf(mn, __shfl_xor(mn, off));
                mx = fmaxf(mx, __shfl_xor(mx, off));
            }
            if (col == 0) {
                int a = aBase + t * 16 + quad * 4 + r;
                if (mn < 1e8f)  atomicMin(&pminK[a], fkey(mn));   // commutative -> deterministic
                if (mx > -1e8f) atomicMax(&pmaxK[a], fkey(mx));
            }
        }
}

// ------------- Kernel 3: per-anchor triplet + loss -------------
__global__ __launch_bounds__(1024) void finalize_kernel(const int* __restrict__ lab,
                                                        const unsigned* __restrict__ pminK,
                                                        const unsigned* __restrict__ pmaxK,
                                                        float* __restrict__ out, int N) {
    float sum = 0.f; int cnt = 0;
    for (int a = threadIdx.x; a < N; a += 1024) {
        int l = lab[a];
        bool ok = (l >= 1 && l <= 6);
        unsigned kp = pminK[a], kn = pmaxK[a];
        if (ok && kp != 0xFFFFFFFFu && kn != 0u) {
            float hp = funkey(kp), hn = funkey(kn);
            float t = MARGIN + hn - hp;
            if (t > 0.f) sum += t;
            cnt += 1;
        }
    }
    #pragma unroll
    for (int off = 32; off >= 1; off >>= 1) {
        sum += __shfl_xor(sum, off);
        cnt += __shfl_xor(cnt, off);
    }
    __shared__ float ssum[16]; __shared__ int scnt[16];
    int w = threadIdx.x >> 6, lane = threadIdx.x & 63;
    if (lane == 0) { ssum[w] = sum; scnt[w] = cnt; }
    __syncthreads();
    if (threadIdx.x == 0) {
        float ts = 0.f; int tc = 0;
        #pragma unroll
        for (int i = 0; i < 16; ++i) { ts += ssum[i]; tc += scnt[i]; }
        out[0] = (tc > 0) ? ts / (float)tc : 0.f;
    }
}

extern "C" void kernel_launch(void* const* d_in, const int* in_sizes, int n_in,
                              void* d_out, int out_size, void* d_ws, size_t ws_size,
                              hipStream_t stream) {
    const float* emb = (const float*)d_in[0];
    const int*   lab = (const int*)d_in[1];
    int N = in_sizes[1];                               // 8192

    unsigned short* ebf  = (unsigned short*)d_ws;      // N*256 bf16 (4 MB)
    unsigned*       pminK = (unsigned*)(ebf + (size_t)N * Hdim);
    unsigned*       pmaxK = pminK + N;

    norm_kernel<<<N / 4, 256, 0, stream>>>(emb, ebf, pminK, pmaxK, N);
    sim_kernel<<<dim3(N / (WPB * MT), NS), 256, 0, stream>>>(ebf, lab, pminK, pmaxK, N);
    finalize_kernel<<<1, 1024, 0, stream>>>(lab, pminK, pmaxK, (float*)d_out, N);
}

// Round 4
// 103.766 us; speedup vs baseline: 6.2499x; 1.8527x over previous
//
#include <hip/hip_runtime.h>
#include <math.h>

#define Hdim    256                    // embedding dim
#define NMAX    8192
#define NCLS    13
#define NPADMAX (NMAX + NCLS * 32)     // buckets padded to 32 rows
#define NBLK    32                     // label-processing blocks (256 labels each)
#define WLMAX   264                    // max 32-anchor wave-tiles
#define NSPLIT  12                     // j-range splits per wave-tile
#define WPB     4                      // waves per block in sim kernel
#define BIGV    1e9f
#define MARGIN  0.5f

typedef __attribute__((ext_vector_type(8))) short bf16x8;   // MFMA A/B frag
typedef __attribute__((ext_vector_type(4))) float f32x4;    // MFMA C/D frag

struct WS {
    unsigned short ebf[NPADMAX][Hdim]; // bucket-sorted normalized bf16 rows
    unsigned hpK[NPADMAX];             // hardest-pos keys (min)
    unsigned hnK[NPADMAX];             // hardest-neg keys (max)
    int labG[NPADMAX];                 // gathered labels (-1 = pad)
    int gpos[NMAX];                    // original row -> gathered row
    int blockHist[NBLK][NCLS];
    int blockBase[NBLK][NCLS];
    int S[NCLS + 1];                   // padded bucket starts (cumulative)
    int n[NCLS];                       // real bucket counts
    int wl_a[WLMAX];                   // worklist: anchor base (gathered)
    int wl_c[WLMAX];                   // worklist: class
    int T;                             // worklist length
};

__device__ inline unsigned short f2bf(float f) {
    unsigned u = __float_as_uint(f);
    return (unsigned short)((u + 0x7fffu + ((u >> 16) & 1u)) >> 16);
}
__device__ inline unsigned fkey(float f) {
    unsigned u = __float_as_uint(f);
    return (u & 0x80000000u) ? ~u : (u | 0x80000000u);
}
__device__ inline float funkey(unsigned k) {
    unsigned u = (k & 0x80000000u) ? (k & 0x7fffffffu) : ~k;
    return __uint_as_float(u);
}

// ---- K1: per-block label histogram + init key/label arrays ----
__global__ __launch_bounds__(256) void hist_init_kernel(const int* __restrict__ lab,
                                                        WS* ws, int N) {
    __shared__ int h[NCLS];
    int tid = threadIdx.x, b = blockIdx.x;
    if (tid < NCLS) h[tid] = 0;
    __syncthreads();
    for (int i = b * 256 + tid; i < N; i += NBLK * 256) {
        int l = lab[i];
        if (l >= 0 && l < NCLS) atomicAdd(&h[l], 1);
    }
    __syncthreads();
    if (tid < NCLS) ws->blockHist[b][tid] = h[tid];
    for (int idx = b * 256 + tid; idx < NPADMAX; idx += NBLK * 256) {
        ws->hpK[idx] = 0xFFFFFFFFu;
        ws->hnK[idx] = 0u;
        ws->labG[idx] = -1;
    }
}

// ---- K2: bucket starts, per-block scatter bases, wave worklist ----
__global__ __launch_bounds__(256) void plan_kernel(WS* ws) {
    __shared__ int sn[NCLS];
    int tid = threadIdx.x;
    if (tid < NCLS) {
        int s = 0;
        for (int b = 0; b < NBLK; ++b) s += ws->blockHist[b][tid];
        sn[tid] = s; ws->n[tid] = s;
    }
    __syncthreads();
    if (tid == 0) {
        int acc = 0;
        for (int c = 0; c < NCLS; ++c) { ws->S[c] = acc; acc += ((sn[c] + 31) >> 5) << 5; }
        ws->S[NCLS] = acc;
    }
    __syncthreads();
    if (tid < NCLS) {
        int base = ws->S[tid];
        for (int b = 0; b < NBLK; ++b) { ws->blockBase[b][tid] = base; base += ws->blockHist[b][tid]; }
    }
    if (tid == 0) {
        int T = 0;
        for (int c = 1; c <= 6; ++c) {
            int nt = (sn[c] + 31) >> 5;
            for (int k = 0; k < nt; ++k) { ws->wl_a[T] = ws->S[c] + 32 * k; ws->wl_c[T] = c; ++T; }
        }
        ws->T = T;
    }
}

// ---- K3: scatter positions via per-block LDS rank ----
__global__ __launch_bounds__(256) void rank_kernel(const int* __restrict__ lab,
                                                   WS* ws, int N) {
    __shared__ int cur[NCLS];
    int tid = threadIdx.x, b = blockIdx.x;
    if (tid < NCLS) cur[tid] = ws->blockBase[b][tid];
    __syncthreads();
    for (int i = b * 256 + tid; i < N; i += NBLK * 256) {
        int l = lab[i];
        int g = -1;
        if (l >= 0 && l < NCLS) g = atomicAdd(&cur[l], 1);
        ws->gpos[i] = g;
        if (g >= 0) ws->labG[g] = l;
    }
}

// ---- K4: L2-normalize rows -> bf16, write to gathered position ----
__global__ __launch_bounds__(256) void norm_gather_kernel(const float* __restrict__ in,
                                                          WS* ws, int N) {
    int row = blockIdx.x * 4 + (threadIdx.x >> 6);
    if (row >= N) return;
    int lane = threadIdx.x & 63;
    int g = ws->gpos[row];                 // wave-uniform
    float4 v = ((const float4*)(in + (size_t)row * Hdim))[lane];
    float ss = v.x*v.x + v.y*v.y + v.z*v.z + v.w*v.w;
    #pragma unroll
    for (int off = 32; off >= 1; off >>= 1) ss += __shfl_xor(ss, off);
    float sc = 1.0f / fmaxf(sqrtf(ss), 1e-12f);
    ushort4 o;
    o.x = f2bf(v.x * sc); o.y = f2bf(v.y * sc);
    o.z = f2bf(v.z * sc); o.w = f2bf(v.w * sc);
    if (g >= 0) ((ushort4*)(&ws->ebf[g][0]))[lane] = o;
}

// ---- K5: bucketed MFMA sim + positional min/max fold ----
// Wave handles 32 anchors (2x16 MFMA tiles) x strided subset of j-tiles over
// [own bucket (min-fold)] ++ [partner bucket (max-fold)]. No LDS, no barriers.
__global__ __launch_bounds__(256) void sim_kernel(WS* ws) {
    const int wave = threadIdx.x >> 6;
    const int lane = threadIdx.x & 63;
    const int col  = lane & 15;
    const int quad = lane >> 4;
    const int wid  = blockIdx.x * WPB + wave;
    const int tileIdx = wid / NSPLIT;
    const int split   = wid % NSPLIT;
    if (tileIdx >= ws->T) return;

    const int aBase = ws->wl_a[tileIdx];
    const int c     = ws->wl_c[tileIdx];
    const int p     = ((c - 1) ^ 1) + 1;            // confused partner: (1,2)(3,4)(5,6)
    const int posS = ws->S[c],  posPadE = ws->S[c + 1], posRealE = posS + ws->n[c];
    const int negS = ws->S[p],  negPadE = ws->S[p + 1], negRealE = negS + ws->n[p];
    const int nPosT = (posPadE - posS) >> 4;
    const int nT    = nPosT + ((negPadE - negS) >> 4);

    const unsigned short* ebf = &ws->ebf[0][0];

    // resident A fragments: frag[m=col][k=quad*8+j]
    bf16x8 afrag[2][8];
    #pragma unroll
    for (int t2 = 0; t2 < 2; ++t2) {
        const unsigned short* rp = ebf + (size_t)(aBase + t2 * 16 + col) * Hdim + quad * 8;
        #pragma unroll
        for (int ks = 0; ks < 8; ++ks)
            afrag[t2][ks] = *(const bf16x8*)(rp + ks * 32);
    }

    float runMin[2][4], runMax[2][4];
    #pragma unroll
    for (int t2 = 0; t2 < 2; ++t2)
        #pragma unroll
        for (int r = 0; r < 4; ++r) { runMin[t2][r] = BIGV; runMax[t2][r] = -BIGV; }

    auto j0Of = [&](int t) -> int {
        return (t < nPosT) ? (posS + (t << 4)) : (negS + ((t - nPosT) << 4));
    };
    bf16x8 b0[8], b1[8];
    auto loadB = [&](bf16x8 (&bf)[8], int t) {
        const unsigned short* rp = ebf + (size_t)(j0Of(t) + col) * Hdim + quad * 8;
        #pragma unroll
        for (int ks = 0; ks < 8; ++ks)
            bf[ks] = *(const bf16x8*)(rp + ks * 32);
    };
    auto computeT = [&](bf16x8 (&bf)[8], int t) {
        int j0 = j0Of(t);
        bool isPos = t < nPosT;                      // wave-uniform
        int realE = isPos ? posRealE : negRealE;
        bool valid = (j0 + col) < realE;             // one v_cmp per tile
        #pragma unroll
        for (int t2 = 0; t2 < 2; ++t2) {
            f32x4 acc = {0.f, 0.f, 0.f, 0.f};
            #pragma unroll
            for (int ks = 0; ks < 8; ++ks)
                acc = __builtin_amdgcn_mfma_f32_16x16x32_bf16(afrag[t2][ks], bf[ks], acc, 0, 0, 0);
            if (isPos) {
                #pragma unroll
                for (int r = 0; r < 4; ++r)
                    runMin[t2][r] = fminf(runMin[t2][r], valid ? acc[r] : BIGV);
            } else {
                #pragma unroll
                for (int r = 0; r < 4; ++r)
                    runMax[t2][r] = fmaxf(runMax[t2][r], valid ? acc[r] : -BIGV);
            }
        }
    };

    // register-double-buffered strided j-tile loop
    int nIter = (nT > split) ? ((nT - split + NSPLIT - 1) / NSPLIT) : 0;
    int t = split, i = 0;
    if (nIter > 0) loadB(b0, t);
    while (i + 2 <= nIter) {
        loadB(b1, t + NSPLIT);
        computeT(b0, t);
        if (i + 2 < nIter) loadB(b0, t + 2 * NSPLIT);
        computeT(b1, t + NSPLIT);
        t += 2 * NSPLIT; i += 2;
    }
    if (i < nIter) computeT(b0, t);

    // reduce across 16 cols, then atomic-key combine (commutative -> deterministic)
    #pragma unroll
    for (int t2 = 0; t2 < 2; ++t2)
        #pragma unroll
        for (int r = 0; r < 4; ++r) {
            float mn = runMin[t2][r], mx = runMax[t2][r];
            #pragma unroll
            for (int off = 1; off < 16; off <<= 1) {
                mn = fminf(mn, __shfl_xor(mn, off));
                mx = fmaxf(mx, __shfl_xor(mx, off));
            }
            if (col == 0) {
                int a = aBase + t2 * 16 + quad * 4 + r;
                if (mn < 1e8f)  atomicMin(&ws->hpK[a], fkey(mn));
                if (mx > -1e8f) atomicMax(&ws->hnK[a], fkey(mx));
            }
        }
}

// ---- K6: per-anchor triplet + loss ----
__global__ __launch_bounds__(1024) void finalize_kernel(WS* ws, float* __restrict__ out) {
    __shared__ int ncls[NCLS];
    if (threadIdx.x < NCLS) ncls[threadIdx.x] = ws->n[threadIdx.x];
    __syncthreads();
    float sum = 0.f; int cnt = 0;
    for (int g = threadIdx.x; g < NPADMAX; g += 1024) {
        int l = ws->labG[g];
        if (l >= 1 && l <= 6) {
            int p = ((l - 1) ^ 1) + 1;
            if (ncls[l] >= 2 && ncls[p] >= 1) {       // has_pos && has_neg
                float hp = funkey(ws->hpK[g]);
                float hn = funkey(ws->hnK[g]);
                float tr = MARGIN + hn - hp;
                if (tr > 0.f) sum += tr;
                cnt += 1;
            }
        }
    }
    #pragma unroll
    for (int off = 32; off >= 1; off >>= 1) {
        sum += __shfl_xor(sum, off);
        cnt += __shfl_xor(cnt, off);
    }
    __shared__ float ssum[16]; __shared__ int scnt[16];
    int w = threadIdx.x >> 6, lane = threadIdx.x & 63;
    if (lane == 0) { ssum[w] = sum; scnt[w] = cnt; }
    __syncthreads();
    if (threadIdx.x == 0) {
        float ts = 0.f; int tc = 0;
        #pragma unroll
        for (int k = 0; k < 16; ++k) { ts += ssum[k]; tc += scnt[k]; }
        out[0] = (tc > 0) ? ts / (float)tc : 0.f;
    }
}

extern "C" void kernel_launch(void* const* d_in, const int* in_sizes, int n_in,
                              void* d_out, int out_size, void* d_ws, size_t ws_size,
                              hipStream_t stream) {
    const float* emb = (const float*)d_in[0];
    const int*   lab = (const int*)d_in[1];
    int N = in_sizes[1];                               // 8192
    WS* ws = (WS*)d_ws;

    hist_init_kernel<<<NBLK, 256, 0, stream>>>(lab, ws, N);
    plan_kernel<<<1, 256, 0, stream>>>(ws);
    rank_kernel<<<NBLK, 256, 0, stream>>>(lab, ws, N);
    norm_gather_kernel<<<(N + 3) / 4, 256, 0, stream>>>(emb, ws, N);
    sim_kernel<<<(WLMAX * NSPLIT + WPB - 1) / WPB, 256, 0, stream>>>(ws);
    finalize_kernel<<<1, 1024, 0, stream>>>(ws, (float*)d_out);
}